// Round 3
// baseline (113.218 us; speedup 1.0000x reference)
//
#include <hip/hip_runtime.h>
#include <hip/hip_fp16.h>
#include <math.h>

#define D_FEAT 128

typedef _Float16 f16x2 __attribute__((ext_vector_type(2)));
struct alignas(16) h8v { f16x2 h[4]; };   // 8 halves = 16B

__device__ __forceinline__ float dot8(const h8v& a, const h8v& b, float acc) {
#if __has_builtin(__builtin_amdgcn_fdot2)
#pragma unroll
    for (int k = 0; k < 4; ++k)
        acc = __builtin_amdgcn_fdot2(a.h[k], b.h[k], acc, false);
#else
#pragma unroll
    for (int k = 0; k < 4; ++k) {
        acc += (float)a.h[k].x * (float)b.h[k].x;
        acc += (float)a.h[k].y * (float)b.h[k].y;
    }
#endif
    return acc;
}

// ---------------- fp32 -> fp16 conversion of x into workspace ----------------
__global__ __launch_bounds__(256) void convert_x_fp16_kernel(
    const float* __restrict__ x, __half* __restrict__ xh, int n_elems)
{
    int i = blockIdx.x * blockDim.x + threadIdx.x;   // 8-element chunk id
    int base = i * 8;
    if (base >= n_elems) return;
    const float4* p = reinterpret_cast<const float4*>(x + base);
    float4 f0 = p[0];
    float4 f1 = p[1];
    __half2 h[4];
    h[0] = __floats2half2_rn(f0.x, f0.y);
    h[1] = __floats2half2_rn(f0.z, f0.w);
    h[2] = __floats2half2_rn(f1.x, f1.y);
    h[3] = __floats2half2_rn(f1.z, f1.w);
    *reinterpret_cast<float4*>(xh + base) = *reinterpret_cast<float4*>(h);
}

// ---------------- fp16 gather + dot + sigmoid, 8 edges per 16-lane group -----
// Each 16-lane group handles 8 edges: 16 independent row-gathers (16B/lane
// each) are all issued before any dependent arithmetic -> 256B/lane in
// flight, 16KB/wave, to maximize memory-level parallelism on the L2-miss
// path. Dot via v_dot2_f32_f16. Lanes 0-7 own one edge each for the final
// sigmoid + store.
__global__ __launch_bounds__(256) void edge_dot_sigmoid_fp16_kernel(
    const __half* __restrict__ xh,
    const int* __restrict__ ei,
    float* __restrict__ out,
    int n_edges)
{
    const int lane = threadIdx.x & 15;               // lane within group
    const int grp  = threadIdx.x >> 4;               // 16 groups per block
    const long eb  = (long)blockIdx.x * 128 + grp * 8;  // first edge of group

    // lanes 0-7 load src indices of edges eb..eb+7; lanes 8-15 load dst.
    int myidx = 0;
    {
        long e = eb + (lane & 7);
        if (e < n_edges)
            myidx = (lane < 8) ? ei[e] : ei[(long)n_edges + e];
    }

    const h8v* __restrict__ xrow = reinterpret_cast<const h8v*>(xh); // 16/row

    h8v a[8], b[8];
#pragma unroll
    for (int k = 0; k < 8; ++k) {
        int sk = __shfl(myidx, k, 16);
        int dk = __shfl(myidx, 8 + k, 16);
        a[k] = xrow[(size_t)sk * 16 + lane];
        b[k] = xrow[(size_t)dk * 16 + lane];
    }

    float r = 0.f;
#pragma unroll
    for (int k = 0; k < 8; ++k) {
        float acc = dot8(a[k], b[k], 0.f);
        acc += __shfl_xor(acc, 1, 16);
        acc += __shfl_xor(acc, 2, 16);
        acc += __shfl_xor(acc, 4, 16);
        acc += __shfl_xor(acc, 8, 16);
        if (lane == k) r = acc;
    }

    if (lane < 8) {
        long e = eb + lane;
        if (e < n_edges)
            out[e] = 1.0f / (1.0f + __expf(-r));
    }
}

// ---------------- fp32 fallback (used only if ws too small) ------------------
__global__ __launch_bounds__(256) void edge_dot_sigmoid_fp32_kernel(
    const float* __restrict__ x,
    const int* __restrict__ ei,
    float* __restrict__ out,
    int n_edges)
{
    const int lane = threadIdx.x & 15;
    const int e = blockIdx.x * 16 + (threadIdx.x >> 4);
    if (e >= n_edges) return;

    const int s = ei[e];
    const int d = ei[n_edges + e];

    const float4* sp = reinterpret_cast<const float4*>(x + (size_t)s * D_FEAT) + lane * 2;
    const float4* dp = reinterpret_cast<const float4*>(x + (size_t)d * D_FEAT) + lane * 2;

    float4 a0 = sp[0], a1 = sp[1], b0 = dp[0], b1 = dp[1];

    float acc = a0.x * b0.x + a0.y * b0.y + a0.z * b0.z + a0.w * b0.w
              + a1.x * b1.x + a1.y * b1.y + a1.z * b1.z + a1.w * b1.w;

    acc += __shfl_xor(acc, 1, 16);
    acc += __shfl_xor(acc, 2, 16);
    acc += __shfl_xor(acc, 4, 16);
    acc += __shfl_xor(acc, 8, 16);

    if (lane == 0) out[e] = 1.0f / (1.0f + __expf(-acc));
}

extern "C" void kernel_launch(void* const* d_in, const int* in_sizes, int n_in,
                              void* d_out, int out_size, void* d_ws, size_t ws_size,
                              hipStream_t stream) {
    const float* x   = (const float*)d_in[0];
    const int*   ei  = (const int*)d_in[1];
    float*       out = (float*)d_out;

    const int n_x     = in_sizes[0];        // n_nodes * 128
    const int n_edges = in_sizes[1] / 2;    // edge_index is [2, E]

    const size_t need = (size_t)n_x * sizeof(__half);
    if (ws_size >= need) {
        __half* xh = (__half*)d_ws;
        int n_chunks = (n_x + 7) / 8;
        convert_x_fp16_kernel<<<(n_chunks + 255) / 256, 256, 0, stream>>>(x, xh, n_x);
        // 128 edges per block
        dim3 grid((n_edges + 127) / 128);
        edge_dot_sigmoid_fp16_kernel<<<grid, 256, 0, stream>>>(xh, ei, out, n_edges);
    } else {
        dim3 grid((n_edges + 15) / 16);
        edge_dot_sigmoid_fp32_kernel<<<grid, 256, 0, stream>>>(x, ei, out, n_edges);
    }
}

// Round 4
// 111.490 us; speedup vs baseline: 1.0155x; 1.0155x over previous
//
#include <hip/hip_runtime.h>
#include <hip/hip_fp16.h>
#include <math.h>

#define D_FEAT 128

typedef _Float16 f16x2 __attribute__((ext_vector_type(2)));
struct alignas(16) h8v { f16x2 h[4]; };   // 8 halves = 16B

__device__ __forceinline__ float dot8(const h8v& a, const h8v& b, float acc) {
#if __has_builtin(__builtin_amdgcn_fdot2)
#pragma unroll
    for (int k = 0; k < 4; ++k)
        acc = __builtin_amdgcn_fdot2(a.h[k], b.h[k], acc, false);
#else
#pragma unroll
    for (int k = 0; k < 4; ++k) {
        acc += (float)a.h[k].x * (float)b.h[k].x;
        acc += (float)a.h[k].y * (float)b.h[k].y;
    }
#endif
    return acc;
}

__device__ __forceinline__ float sigmoid_fast(float x) {
    // sigmoid(x) = 1/(1+e^-x); e^-x = 2^(-x*log2(e)) -> native v_exp_f32
    return 1.0f / (1.0f + __builtin_exp2f(-1.44269504f * x));
}

// ---------------- fp32 -> fp16 conversion of x into workspace ----------------
__global__ __launch_bounds__(256) void convert_x_fp16_kernel(
    const float* __restrict__ x, __half* __restrict__ xh, int n_elems)
{
    int i = blockIdx.x * blockDim.x + threadIdx.x;   // 8-element chunk id
    int base = i * 8;
    if (base >= n_elems) return;
    const float4* p = reinterpret_cast<const float4*>(x + base);
    float4 f0 = p[0];
    float4 f1 = p[1];
    __half2 h[4];
    h[0] = __floats2half2_rn(f0.x, f0.y);
    h[1] = __floats2half2_rn(f0.z, f0.w);
    h[2] = __floats2half2_rn(f1.x, f1.y);
    h[3] = __floats2half2_rn(f1.z, f1.w);
    *reinterpret_cast<float4*>(xh + base) = *reinterpret_cast<float4*>(h);
}

// ---------------- fp16 gather + dot + sigmoid ----------------
// Round-2 structure (best measured): 16-lane group per edge, 2 edges per
// group per block so all 4 row-loads (16B/lane each) are in flight before
// any dependent math; dot via v_dot2_f32_f16; 4-step shfl_xor reduce.
__global__ __launch_bounds__(256) void edge_dot_sigmoid_fp16_kernel(
    const __half* __restrict__ xh,
    const int* __restrict__ ei,
    float* __restrict__ out,
    int n_edges)
{
    const int lane = threadIdx.x & 15;
    const int grp  = threadIdx.x >> 4;            // 16 groups per block
    const int base = blockIdx.x * 32;             // 32 edges per block
    const int e0 = base + grp;
    const int e1 = base + 16 + grp;

    if (e0 >= n_edges) return;

    const int s0 = ei[e0];
    const int d0 = ei[n_edges + e0];
    const bool has1 = (e1 < n_edges);
    const int s1 = has1 ? ei[e1] : s0;
    const int d1 = has1 ? ei[n_edges + e1] : d0;

    const h8v* __restrict__ xrow = reinterpret_cast<const h8v*>(xh); // 16/row

    h8v a0 = xrow[(size_t)s0 * 16 + lane];
    h8v b0 = xrow[(size_t)d0 * 16 + lane];
    h8v a1 = xrow[(size_t)s1 * 16 + lane];
    h8v b1 = xrow[(size_t)d1 * 16 + lane];

    float acc0 = dot8(a0, b0, 0.f);
    float acc1 = dot8(a1, b1, 0.f);

    acc0 += __shfl_xor(acc0, 1, 16);
    acc0 += __shfl_xor(acc0, 2, 16);
    acc0 += __shfl_xor(acc0, 4, 16);
    acc0 += __shfl_xor(acc0, 8, 16);

    acc1 += __shfl_xor(acc1, 1, 16);
    acc1 += __shfl_xor(acc1, 2, 16);
    acc1 += __shfl_xor(acc1, 4, 16);
    acc1 += __shfl_xor(acc1, 8, 16);

    if (lane == 0) {
        out[e0] = sigmoid_fast(acc0);
        if (has1) out[e1] = sigmoid_fast(acc1);
    }
}

// ---------------- fp32 fallback (used only if ws too small) ------------------
__global__ __launch_bounds__(256) void edge_dot_sigmoid_fp32_kernel(
    const float* __restrict__ x,
    const int* __restrict__ ei,
    float* __restrict__ out,
    int n_edges)
{
    const int lane = threadIdx.x & 15;
    const int e = blockIdx.x * 16 + (threadIdx.x >> 4);
    if (e >= n_edges) return;

    const int s = ei[e];
    const int d = ei[n_edges + e];

    const float4* sp = reinterpret_cast<const float4*>(x + (size_t)s * D_FEAT) + lane * 2;
    const float4* dp = reinterpret_cast<const float4*>(x + (size_t)d * D_FEAT) + lane * 2;

    float4 a0 = sp[0], a1 = sp[1], b0 = dp[0], b1 = dp[1];

    float acc = a0.x * b0.x + a0.y * b0.y + a0.z * b0.z + a0.w * b0.w
              + a1.x * b1.x + a1.y * b1.y + a1.z * b1.z + a1.w * b1.w;

    acc += __shfl_xor(acc, 1, 16);
    acc += __shfl_xor(acc, 2, 16);
    acc += __shfl_xor(acc, 4, 16);
    acc += __shfl_xor(acc, 8, 16);

    if (lane == 0) out[e] = sigmoid_fast(acc);
}

extern "C" void kernel_launch(void* const* d_in, const int* in_sizes, int n_in,
                              void* d_out, int out_size, void* d_ws, size_t ws_size,
                              hipStream_t stream) {
    const float* x   = (const float*)d_in[0];
    const int*   ei  = (const int*)d_in[1];
    float*       out = (float*)d_out;

    const int n_x     = in_sizes[0];        // n_nodes * 128
    const int n_edges = in_sizes[1] / 2;    // edge_index is [2, E]

    const size_t need = (size_t)n_x * sizeof(__half);
    if (ws_size >= need) {
        __half* xh = (__half*)d_ws;
        int n_chunks = (n_x + 7) / 8;
        convert_x_fp16_kernel<<<(n_chunks + 255) / 256, 256, 0, stream>>>(x, xh, n_x);
        dim3 grid((n_edges + 31) / 32);
        edge_dot_sigmoid_fp16_kernel<<<grid, 256, 0, stream>>>(xh, ei, out, n_edges);
    } else {
        dim3 grid((n_edges + 15) / 16);
        edge_dot_sigmoid_fp32_kernel<<<grid, 256, 0, stream>>>(x, ei, out, n_edges);
    }
}